// Round 10
// baseline (328.487 us; speedup 1.0000x reference)
//
#include <hip/hip_runtime.h>
#include <hip/hip_bf16.h>
#include <string.h>

// Batched GEMM: out[b,o,f] = sum_i W[b,o,i] * x[b,i,f]
// B=32, M(O)=1024, K(I)=1024, N(F)=2048, fp32 in/out, bf16 MFMA compute.
//
// Round-10: occupancy play. 128x128 tile, 256 thr, 4 waves (wave tile
// 64x64), BK=32, LSTR=36 (18-bank rows, conflict-light per r5/r8 data).
// LDS 36.9 KB + VGPR ~140 (launch_bounds(256,3)) -> ~3 blocks/CU
// (12 waves, 3/SIMD): cross-block TLP hides the staging/barrier chain
// that kept the 256^2 variants at 22% occupancy / 23% MfmaUtil.
// r6's proven 2-phase loop: reg-staged cvt_pk -> LDS, double buffer,
// lgkm-only barrier, t+2 prefetch, setprio MFMA. XCD-chunked swizzle
// (4096 blocks, 512/XCD, n fastest -> W panel L2 reuse).

typedef float  f32x2 __attribute__((ext_vector_type(2)));
typedef float  f32x4 __attribute__((ext_vector_type(4)));
typedef short  bf16x8 __attribute__((ext_vector_type(8)));
typedef unsigned int u32;

#define BATCH 32
#define MDIM 1024
#define KDIM 1024
#define NDIM 2048
#define BM 128
#define BN 128
#define BK 32
#define NT (KDIM / BK)   // 32 K-steps
#define LSTR 36          // ushorts per LDS row: 32 data + 4 pad (18 banks)

__device__ __forceinline__ u32 cvt2(float a, float b) {
    float2 t; t.x = a; t.y = b;
    __hip_bfloat162 h = __float22bfloat162_rn(t);   // v_cvt_pk_bf16_f32 (RTNE)
    u32 r; memcpy(&r, &h, 4);
    return r;
}

// Barrier that does NOT drain vmcnt: LDS visibility only.
__device__ __forceinline__ void lds_barrier() {
    asm volatile("s_waitcnt lgkmcnt(0)" ::: "memory");
    __builtin_amdgcn_s_barrier();
    asm volatile("" ::: "memory");
}

__global__ __launch_bounds__(256, 3) void bgemm_bf16_kernel(
    const float* __restrict__ x, const float* __restrict__ w,
    float* __restrict__ out)
{
    __shared__ unsigned short Ab[2][BM * LSTR];   // W tile  [m][k]  9.2 KB each
    __shared__ unsigned short Bb[2][BN * LSTR];   // x tile^T [n][k] 9.2 KB each

    // ---- XCD-chunked bijective block swizzle (4096 blocks, 4096%8==0) ----
    const int bid  = blockIdx.x;
    const int lbid = (bid & 7) * 512 + (bid >> 3);
    const int bx = lbid & 15;         // n-tile (fastest -> W panel reuse)
    const int by = (lbid >> 4) & 7;   // m-tile
    const int bz = lbid >> 7;         // batch

    const int tid = threadIdx.x;
    const int m0  = by * BM;
    const int n0  = bx * BN;

    const int lane = tid & 63;
    const int wid  = tid >> 6;
    const int wm   = (wid >> 1) * 64;    // wave tile 64x64
    const int wn   = (wid & 1)  * 64;
    const int l15  = lane & 15;
    const int kg8  = (lane >> 4) * 8;

    const float* Ag = w + (size_t)bz * MDIM * KDIM + (size_t)m0 * KDIM;
    const float* Bg = x + (size_t)bz * KDIM * NDIM + n0;
    float*       Cg = out + (size_t)bz * MDIM * NDIM + (size_t)m0 * NDIM + n0;

    // ---- A staging map: thread -> rows (tid>>3)+32i (i=0..3), f32x4 col tid&7
    const int a_k4 = tid & 7;
    const int a_m0 = tid >> 3;           // 0..31
    int a_idx[4];
    #pragma unroll
    for (int i = 0; i < 4; ++i)
        a_idx[i] = (a_m0 + 32 * i) * LSTR + 4 * a_k4;
    // ---- B staging map: thread -> k rows 8*(tid>>6)+j, n cols 2*(tid&63)+c
    const int bn0  = 2 * (tid & 63);
    const int b_k0 = 8 * (tid >> 6);     // 0,8,16,24
    int b_idx[2];
    #pragma unroll
    for (int c = 0; c < 2; ++c)
        b_idx[c] = (bn0 + c) * LSTR + b_k0;
    // ---- frag read addrs ----
    int rd_a[4], rd_b[4];
    #pragma unroll
    for (int mi = 0; mi < 4; ++mi)
        rd_a[mi] = (wm + mi * 16 + l15) * LSTR + kg8;
    #pragma unroll
    for (int ni = 0; ni < 4; ++ni)
        rd_b[ni] = (wn + ni * 16 + l15) * LSTR + kg8;

    const float* Ap = Ag + (size_t)a_m0 * KDIM + 4 * a_k4;
    const float* Bp = Bg + (size_t)b_k0 * NDIM + bn0;

    f32x4 acc[4][4];
    #pragma unroll
    for (int i = 0; i < 4; ++i)
        #pragma unroll
        for (int j = 0; j < 4; ++j)
            acc[i][j] = f32x4{0.f, 0.f, 0.f, 0.f};

    f32x4 aav[4];
    f32x2 bbv[8];

    auto load_regs = [&](int kt) {
        #pragma unroll
        for (int i = 0; i < 4; ++i)
            aav[i] = *reinterpret_cast<const f32x4*>(
                Ap + (size_t)(32 * i) * KDIM + kt);
        #pragma unroll
        for (int j = 0; j < 8; ++j)
            bbv[j] = *reinterpret_cast<const f32x2*>(
                Bp + (size_t)(kt + j) * NDIM);
    };
    auto stage = [&](int s) {
        #pragma unroll
        for (int i = 0; i < 4; ++i) {
            uint2 v = make_uint2(cvt2(aav[i][0], aav[i][1]),
                                 cvt2(aav[i][2], aav[i][3]));
            *reinterpret_cast<uint2*>(&Ab[s][a_idx[i]]) = v;   // ds_write_b64
        }
        #pragma unroll
        for (int c = 0; c < 2; ++c) {
            uint4 v = make_uint4(cvt2(bbv[0][c], bbv[1][c]),
                                 cvt2(bbv[2][c], bbv[3][c]),
                                 cvt2(bbv[4][c], bbv[5][c]),
                                 cvt2(bbv[6][c], bbv[7][c]));
            *reinterpret_cast<uint4*>(&Bb[s][b_idx[c]]) = v;   // ds_write_b128
        }
    };
    auto compute = [&](int s) {
        bf16x8 bfr[4];
        #pragma unroll
        for (int ni = 0; ni < 4; ++ni)
            bfr[ni] = *reinterpret_cast<const bf16x8*>(&Bb[s][rd_b[ni]]);
        __builtin_amdgcn_s_setprio(1);
        #pragma unroll
        for (int mi = 0; mi < 4; ++mi) {
            bf16x8 af = *reinterpret_cast<const bf16x8*>(&Ab[s][rd_a[mi]]);
            #pragma unroll
            for (int ni = 0; ni < 4; ++ni)
                acc[mi][ni] = __builtin_amdgcn_mfma_f32_16x16x32_bf16(
                    af, bfr[ni], acc[mi][ni], 0, 0, 0);
        }
        __builtin_amdgcn_s_setprio(0);
    };

    // ---- prologue ----
    load_regs(0);
    stage(0);
    load_regs(BK);
    lds_barrier();

    // ---- main loop ----
    for (int t = 0; t < NT - 1; ++t) {
        const int cur = t & 1;
        stage(cur ^ 1);                       // tile t+1 -> other buffer
        int kt2 = (t + 2) * BK;               // issue loads for t+2
        if (kt2 > KDIM - BK) kt2 = KDIM - BK; // clamp (last value unused)
        load_regs(kt2);
        compute(cur);                         // tile t
        lds_barrier();
    }
    compute((NT - 1) & 1);                    // last tile

    // ---- C store: D layout col=lane&15, row=(lane>>4)*4+reg ----
    const int rbase = (lane >> 4) * 4;
    #pragma unroll
    for (int mi = 0; mi < 4; ++mi) {
        #pragma unroll
        for (int ni = 0; ni < 4; ++ni) {
            int n  = wn + ni * 16 + l15;
            int mb = wm + mi * 16 + rbase;
            #pragma unroll
            for (int r = 0; r < 4; ++r)
                Cg[(size_t)(mb + r) * NDIM + n] = acc[mi][ni][r];
        }
    }
}

extern "C" void kernel_launch(void* const* d_in, const int* in_sizes, int n_in,
                              void* d_out, int out_size, void* d_ws, size_t ws_size,
                              hipStream_t stream) {
    const float* x = (const float*)d_in[0];   // [32][1024][2048]
    const float* w = (const float*)d_in[1];   // [32][1024][1024]
    float* out = (float*)d_out;               // [32][1024][2048]
    const int nblocks = (NDIM / BN) * (MDIM / BM) * BATCH;  // 16*8*32 = 4096
    bgemm_bf16_kernel<<<dim3(nblocks), dim3(256), 0, stream>>>(x, w, out);
}

// Round 11
// 259.316 us; speedup vs baseline: 1.2667x; 1.2667x over previous
//
#include <hip/hip_runtime.h>
#include <hip/hip_bf16.h>
#include <string.h>

// Batched GEMM: out[b,o,f] = sum_i W[b,o,i] * x[b,i,f]
// B=32, M(O)=1024, K(I)=1024, N(F)=2048, fp32 in/out, bf16 MFMA compute.
//
// Round-11: PRODUCER-CONSUMER wave specialization. 768 threads = 12 waves:
//   waves 0-3  = producers: global fp32 -> cvt_pk bf16 -> LDS (all staging)
//   waves 4-11 = consumers: ds_read frags -> MFMA only (never wait on vmcnt)
// Only consumers carry the 128-AGPR accumulator; with launch_bounds(768,3)
// each wave stays <=170 unified regs -> 3 waves/SIMD = 1 producer + 2
// consumers co-resident per SIMD. Producer's load/cvt/write chain overlaps
// consumers' MFMA on separate pipes; producer loads are issued one K-step
// ahead so their HBM/L2 latency is pre-hidden.
// 256x256 tile, BK=32, LSTR=34 (17-bank rows: <=2-way banks on A b64
// writes, B b128 writes, frag b128 reads). Double buffer, one lgkm-only
// barrier per K-step (stage t+1 || compute t). XCD-chunked block swizzle.

typedef float  f32x4 __attribute__((ext_vector_type(4)));
typedef short  bf16x8 __attribute__((ext_vector_type(8)));
typedef unsigned int u32;

#define BATCH 32
#define MDIM 1024
#define KDIM 1024
#define NDIM 2048
#define BM 256
#define BN 256
#define BK 32
#define NT (KDIM / BK)   // 32 K-steps
#define LSTR 34          // ushorts per LDS row: 32 data + 2 pad (17 banks)

__device__ __forceinline__ u32 cvt2(float a, float b) {
    float2 t; t.x = a; t.y = b;
    __hip_bfloat162 h = __float22bfloat162_rn(t);   // v_cvt_pk_bf16_f32 (RTNE)
    u32 r; memcpy(&r, &h, 4);
    return r;
}

// Barrier that does NOT drain vmcnt: LDS visibility only.
__device__ __forceinline__ void lds_barrier() {
    asm volatile("s_waitcnt lgkmcnt(0)" ::: "memory");
    __builtin_amdgcn_s_barrier();
    asm volatile("" ::: "memory");
}

__global__ __launch_bounds__(768, 3) void bgemm_pc_kernel(
    const float* __restrict__ x, const float* __restrict__ w,
    float* __restrict__ out)
{
    __shared__ unsigned short Ab[2][BM * LSTR];   // W tile  [m][k]
    __shared__ unsigned short Bb[2][BN * LSTR];   // x tile^T [n][k]  (total 69.6 KB)

    // ---- XCD-chunked bijective block swizzle (1024 blocks, 1024%8==0) ----
    const int bid  = blockIdx.x;
    const int lbid = (bid & 7) * 128 + (bid >> 3);
    const int bx = lbid & 7;          // n-tile
    const int by = (lbid >> 3) & 3;   // m-tile
    const int bz = lbid >> 5;         // batch

    const int tid  = threadIdx.x;
    const int wid  = tid >> 6;
    const int lane = tid & 63;

    const float* Ag = w + (size_t)bz * MDIM * KDIM + (size_t)(by * BM) * KDIM;
    const float* Bg = x + (size_t)bz * KDIM * NDIM + bx * BN;

    if (wid < 4) {
        // ================= PRODUCERS (256 threads) =================
        // A: 256 rows x 32 k. thread -> rows (tid>>3)+32i (i=0..7), f32x4 col tid&7
        const int a_k4 = tid & 7;
        const int a_m0 = tid >> 3;        // 0..31
        int a_idx[8];
        #pragma unroll
        for (int i = 0; i < 8; ++i)
            a_idx[i] = (a_m0 + 32 * i) * LSTR + 4 * a_k4;
        // B: 32 k-rows x 256 n. thread -> k rows 8*wid+j (j=0..7), n cols 4*(tid&63)+c
        const int bn0  = 4 * (tid & 63);
        const int b_k0 = 8 * (tid >> 6);  // 0,8,16,24
        int b_idx[4];
        #pragma unroll
        for (int c = 0; c < 4; ++c)
            b_idx[c] = (bn0 + c) * LSTR + b_k0;

        const float* Ap = Ag + (size_t)a_m0 * KDIM + 4 * a_k4;
        const float* Bp = Bg + (size_t)b_k0 * NDIM + bn0;

        f32x4 aav[8], bbv[8];
        auto load_regs = [&](int kt) {
            #pragma unroll
            for (int i = 0; i < 8; ++i)
                aav[i] = *reinterpret_cast<const f32x4*>(
                    Ap + (size_t)(32 * i) * KDIM + kt);
            #pragma unroll
            for (int j = 0; j < 8; ++j)
                bbv[j] = *reinterpret_cast<const f32x4*>(
                    Bp + (size_t)(kt + j) * NDIM);
        };
        auto stage = [&](int s) {
            #pragma unroll
            for (int i = 0; i < 8; ++i) {
                uint2 v = make_uint2(cvt2(aav[i][0], aav[i][1]),
                                     cvt2(aav[i][2], aav[i][3]));
                *reinterpret_cast<uint2*>(&Ab[s][a_idx[i]]) = v;   // ds_write_b64
            }
            #pragma unroll
            for (int c = 0; c < 4; ++c) {
                uint4 v = make_uint4(cvt2(bbv[0][c], bbv[1][c]),
                                     cvt2(bbv[2][c], bbv[3][c]),
                                     cvt2(bbv[4][c], bbv[5][c]),
                                     cvt2(bbv[6][c], bbv[7][c]));
                *reinterpret_cast<uint4*>(&Bb[s][b_idx[c]]) = v;   // ds_write_b128
            }
        };

        load_regs(0);
        stage(0);
        load_regs(BK);          // tile 1 loads in flight across barrier[0]
        lds_barrier();          // barrier[0]
        for (int t = 1; t < NT; ++t) {
            stage(t & 1);       // regs loaded one full window ago -> no stall
            if (t + 1 < NT)
                load_regs((t + 1) * BK);
            lds_barrier();      // barrier[t]
        }
        // producers exit; no further barriers on either side
    } else {
        // ================= CONSUMERS (512 threads, 8 waves) =================
        const int cw  = wid - 4;
        const int wm  = (cw >> 1) * 64;    // wave tile 64x128
        const int wn  = (cw & 1) * 128;
        const int l15 = lane & 15;
        const int kg8 = (lane >> 4) * 8;

        int rd_a[4], rd_b[8];
        #pragma unroll
        for (int mi = 0; mi < 4; ++mi)
            rd_a[mi] = (wm + mi * 16 + l15) * LSTR + kg8;
        #pragma unroll
        for (int ni = 0; ni < 8; ++ni)
            rd_b[ni] = (wn + ni * 16 + l15) * LSTR + kg8;

        f32x4 acc[4][8];
        #pragma unroll
        for (int i = 0; i < 4; ++i)
            #pragma unroll
            for (int j = 0; j < 8; ++j)
                acc[i][j] = f32x4{0.f, 0.f, 0.f, 0.f};

        lds_barrier();          // barrier[0]: tile 0 ready
        for (int t = 0; t < NT; ++t) {
            const int s = t & 1;
            bf16x8 af[4];
            #pragma unroll
            for (int mi = 0; mi < 4; ++mi)
                af[mi] = *reinterpret_cast<const bf16x8*>(&Ab[s][rd_a[mi]]);
            #pragma unroll
            for (int ni = 0; ni < 8; ++ni) {
                bf16x8 bfr = *reinterpret_cast<const bf16x8*>(&Bb[s][rd_b[ni]]);
                #pragma unroll
                for (int mi = 0; mi < 4; ++mi)
                    acc[mi][ni] = __builtin_amdgcn_mfma_f32_16x16x32_bf16(
                        af[mi], bfr, acc[mi][ni], 0, 0, 0);
            }
            if (t < NT - 1) lds_barrier();   // barriers[1..NT-1]
        }

        // ---- C store: D layout col=lane&15, row=(lane>>4)*4+reg ----
        float* Cg = out + (size_t)bz * MDIM * NDIM
                        + (size_t)(by * BM) * NDIM + bx * BN;
        const int rbase = (lane >> 4) * 4;
        #pragma unroll
        for (int mi = 0; mi < 4; ++mi) {
            #pragma unroll
            for (int ni = 0; ni < 8; ++ni) {
                int n  = wn + ni * 16 + l15;
                int mb = wm + mi * 16 + rbase;
                #pragma unroll
                for (int r = 0; r < 4; ++r)
                    Cg[(size_t)(mb + r) * NDIM + n] = acc[mi][ni][r];
            }
        }
    }
}

extern "C" void kernel_launch(void* const* d_in, const int* in_sizes, int n_in,
                              void* d_out, int out_size, void* d_ws, size_t ws_size,
                              hipStream_t stream) {
    const float* x = (const float*)d_in[0];   // [32][1024][2048]
    const float* w = (const float*)d_in[1];   // [32][1024][1024]
    float* out = (float*)d_out;               // [32][1024][2048]
    const int nblocks = (NDIM / BN) * (MDIM / BM) * BATCH;  // 8*4*32 = 1024
    bgemm_pc_kernel<<<dim3(nblocks), dim3(768), 0, stream>>>(x, w, out);
}